// Round 1
// baseline (126.372 us; speedup 1.0000x reference)
//
#include <hip/hip_runtime.h>
#include <stdint.h>

#define NROWS 8192
#define KDIM  512
#define BM    128
#define BK    32
#define NT    (NROWS / BM)   // 64 tiles per dim

typedef __attribute__((ext_vector_type(8))) short bf16x8;
typedef __attribute__((ext_vector_type(4))) float f32x4;

__device__ __forceinline__ unsigned short f32_to_bf16(float f) {
  union { float f; unsigned int u; } v; v.f = f;
  unsigned int u = v.u;
  u += 0x7FFFu + ((u >> 16) & 1u);   // round-to-nearest-even
  return (unsigned short)(u >> 16);
}

// global -> LDS async copy, 16 B per lane. LDS dest is wave-uniform base +
// lane*16 (hardware semantics) -- our lane->LDS mapping is exactly linear.
__device__ __forceinline__ void async_copy16(const unsigned short* g, unsigned short* l) {
  __builtin_amdgcn_global_load_lds(
      (const __attribute__((address_space(1))) unsigned int*)g,
      (__attribute__((address_space(3))) unsigned int*)l,
      16, 0, 0);
}

// Kernel 1: row-normalize fp32 -> bf16 (RNE). Block 0 also zeroes the accumulator.
__global__ __launch_bounds__(256) void prep_kernel(
    const float* __restrict__ src, unsigned short* __restrict__ dst,
    float* __restrict__ acc) {
  const int row = blockIdx.x;
  const int tid = threadIdx.x;
  const float v0 = src[row * KDIM + tid];
  const float v1 = src[row * KDIM + tid + 256];
  float ss = v0 * v0 + v1 * v1;
  #pragma unroll
  for (int off = 32; off > 0; off >>= 1) ss += __shfl_down(ss, off);
  __shared__ float red[4];
  __shared__ float s_rn;
  const int lane = tid & 63, w = tid >> 6;
  if (lane == 0) red[w] = ss;
  __syncthreads();
  if (tid == 0) {
    const float s = red[0] + red[1] + red[2] + red[3];
    s_rn = 1.0f / sqrtf(s);          // norms ~22.6, EPS=1e-8 can never fire
    if (row == 0) *acc = 0.0f;       // zero global accumulator each launch
  }
  __syncthreads();
  const float rn = s_rn;
  dst[row * KDIM + tid]       = f32_to_bf16(v0 * rn);
  dst[row * KDIM + tid + 256] = f32_to_bf16(v1 * rn);
}

// Kernel 2: tiled bf16 MFMA GEMM (idn @ idn^T) fused with clamp-at-zero,
// diagonal masking, and full reduction. Upper-triangular tiles only; strictly
// upper tiles are weighted 2x by symmetry.
__global__ __launch_bounds__(256) void sim_reduce_kernel(
    const unsigned short* __restrict__ idn, float* __restrict__ acc) {
  const int bi = blockIdx.y;
  const int bj = blockIdx.x;
  if (bj < bi) return;               // block-uniform early exit

  __shared__ __align__(16) unsigned short As[BM * BK];
  __shared__ __align__(16) unsigned short Bs[BM * BK];
  __shared__ float red[4];

  const int tid  = threadIdx.x;      // 0..255, 4 waves
  const int lane = tid & 63;
  const int w    = tid >> 6;
  const int wr   = (w >> 1) * 64;    // wave's 64x64 quadrant
  const int wc   = (w & 1) * 64;
  const int q    = lane >> 4;        // 0..3
  const int r16  = lane & 15;        // 0..15

  f32x4 acc_f[4][4];
  #pragma unroll
  for (int i = 0; i < 4; i++)
    #pragma unroll
    for (int j = 0; j < 4; j++)
      acc_f[i][j] = (f32x4){0.f, 0.f, 0.f, 0.f};

  // Staging: each tile is 512 chunks of 16 B; thread t covers chunks t, t+256.
  // Chunk c = row (c>>2), k-elements [(c&3)*8, +8): LDS byte offset c*16 is
  // exactly row-major [row][k] -- lane-linear as global_load_lds requires.
  const int c0 = tid, c1 = tid + 256;
  const unsigned short* gA0 = idn + (bi * BM + (c0 >> 2)) * KDIM + (c0 & 3) * 8;
  const unsigned short* gA1 = idn + (bi * BM + (c1 >> 2)) * KDIM + (c1 & 3) * 8;
  const unsigned short* gB0 = idn + (bj * BM + (c0 >> 2)) * KDIM + (c0 & 3) * 8;
  const unsigned short* gB1 = idn + (bj * BM + (c1 >> 2)) * KDIM + (c1 & 3) * 8;
  unsigned short* lA0 = As + c0 * 8;
  unsigned short* lA1 = As + c1 * 8;
  unsigned short* lB0 = Bs + c0 * 8;
  unsigned short* lB1 = Bs + c1 * 8;

  for (int k0 = 0; k0 < KDIM; k0 += BK) {
    async_copy16(gA0 + k0, lA0);
    async_copy16(gA1 + k0, lA1);
    async_copy16(gB0 + k0, lB0);
    async_copy16(gB1 + k0, lB1);
    asm volatile("s_waitcnt vmcnt(0)" ::: "memory");
    __syncthreads();

    bf16x8 a[4], b[4];
    #pragma unroll
    for (int mi = 0; mi < 4; mi++)   // A frag: row = lane&15, k = (lane>>4)*8+j
      a[mi] = *(const bf16x8*)&As[(wr + mi * 16 + r16) * BK + q * 8];
    #pragma unroll
    for (int ni = 0; ni < 4; ni++)   // B^T frag: same pattern on Bs
      b[ni] = *(const bf16x8*)&Bs[(wc + ni * 16 + r16) * BK + q * 8];
    #pragma unroll
    for (int mi = 0; mi < 4; mi++)
      #pragma unroll
      for (int ni = 0; ni < 4; ni++)
        acc_f[mi][ni] = __builtin_amdgcn_mfma_f32_16x16x32_bf16(
            a[mi], b[ni], acc_f[mi][ni], 0, 0, 0);
    __syncthreads();
  }

  // Epilogue: clamp at zero, mask diagonal (diagonal blocks only), reduce.
  // C/D layout (verified m89/m91): col = lane&15, row = (lane>>4)*4 + reg.
  float local = 0.f;
  const bool diag = (bi == bj);
  #pragma unroll
  for (int mi = 0; mi < 4; mi++)
    #pragma unroll
    for (int ni = 0; ni < 4; ni++)
      #pragma unroll
      for (int rr = 0; rr < 4; rr++) {
        const int ri = wr + mi * 16 + q * 4 + rr;
        const int ci = wc + ni * 16 + r16;
        float v = fmaxf(acc_f[mi][ni][rr], 0.f);
        if (diag && ri == ci) v = 0.f;
        local += v;
      }

  #pragma unroll
  for (int off = 32; off > 0; off >>= 1) local += __shfl_down(local, off);
  if (lane == 0) red[w] = local;
  __syncthreads();
  if (tid == 0) {
    float s = red[0] + red[1] + red[2] + red[3];
    if (!diag) s *= 2.f;             // strictly-upper tiles stand in for both triangles
    atomicAdd(acc, s);
  }
}

// Kernel 3: scale and write both outputs (total_loss == l_id_div, DIV_COEF=1).
__global__ void finalize_kernel(const float* __restrict__ acc, float* __restrict__ out) {
  const float m = *acc * (1.0f / ((float)NROWS * (float)NROWS));
  out[0] = m;
  out[1] = m;
}

extern "C" void kernel_launch(void* const* d_in, const int* in_sizes, int n_in,
                              void* d_out, int out_size, void* d_ws, size_t ws_size,
                              hipStream_t stream) {
  const float* id = (const float*)d_in[0];
  float* out = (float*)d_out;
  unsigned short* idn = (unsigned short*)d_ws;                       // 8192*512 bf16 = 8 MB
  float* acc = (float*)((char*)d_ws + (size_t)NROWS * KDIM * 2);     // 4 B accumulator

  prep_kernel<<<NROWS, 256, 0, stream>>>(id, idn, acc);
  dim3 grid(NT, NT);
  sim_reduce_kernel<<<grid, 256, 0, stream>>>(idn, acc);
  finalize_kernel<<<1, 1, 0, stream>>>(acc, out);
}